// Round 10
// baseline (508.275 us; speedup 1.0000x reference)
//
#include <hip/hip_runtime.h>
#include <hip/hip_fp16.h>

#define N_NODES 100000
#define N_EDGES 1600000

// ---------------- degree (XCD-partitioned: cnt lines stay in one L2) --------
__global__ __launch_bounds__(256) void degree_kernel(const int* __restrict__ dst,
                                                     int* __restrict__ cnt, int E) {
    const int range = blockIdx.x & 7;
    const int lo = range * (N_NODES / 8);
    const int hi = lo + (N_NODES / 8);
    int i = (blockIdx.x >> 3) * blockDim.x + threadIdx.x;
    const int stride = (gridDim.x >> 3) * blockDim.x;
    for (; i < E; i += stride) {
        const int d = dst[i];
        if (d >= lo && d < hi) atomicAdd(&cnt[d], 1);
    }
}

__global__ __launch_bounds__(256) void inv_kernel(const int* __restrict__ cnt,
                                                  float* __restrict__ inv, int N) {
    int i = blockIdx.x * blockDim.x + threadIdx.x;
    if (i < N) inv[i] = (cnt[i] > 0) ? (1.0f / (float)cnt[i]) : 0.0f;
}

// ---------------- x padded to [N,8] fp32 (32B rows, 3.2MB: L2-resident) -----
__global__ __launch_bounds__(256) void pad_x_kernel(const float* __restrict__ x,
                                                    float* __restrict__ x8, int N) {
    int i = blockIdx.x * blockDim.x + threadIdx.x;  // one float4 half-row each
    if (i >= 2 * N) return;
    const int n = i >> 1, h = i & 1;
    float4 v;
    if (h == 0) v = make_float4(x[n * 6 + 0], x[n * 6 + 1], x[n * 6 + 2], x[n * 6 + 3]);
    else        v = make_float4(x[n * 6 + 4], x[n * 6 + 5], 0.0f, 0.0f);
    ((float4*)x8)[i] = v;
}

// ---------------- hierarchical exclusive scan (cnt -> cursor) ----------------
__global__ __launch_bounds__(256) void block_sum_kernel(const int* __restrict__ cnt,
                                                        int* __restrict__ bsum, int N) {
    __shared__ int s[256];
    const int tid = threadIdx.x;
    const int i = blockIdx.x * 256 + tid;
    s[tid] = (i < N) ? cnt[i] : 0;
    __syncthreads();
#pragma unroll
    for (int d = 128; d > 0; d >>= 1) {
        if (tid < d) s[tid] += s[tid + d];
        __syncthreads();
    }
    if (tid == 0) bsum[blockIdx.x] = s[0];
}

__global__ __launch_bounds__(512) void scan_bsum_kernel(int* __restrict__ bsum, int NB) {
    __shared__ int s[512];
    const int tid = threadIdx.x;
    const int v = (tid < NB) ? bsum[tid] : 0;
    s[tid] = v;
    __syncthreads();
    for (int d = 1; d < 512; d <<= 1) {
        const int t = (tid >= d) ? s[tid - d] : 0;
        __syncthreads();
        s[tid] += t;
        __syncthreads();
    }
    if (tid < NB) bsum[tid] = s[tid] - v;  // exclusive
}

__global__ __launch_bounds__(256) void make_cursor_kernel(const int* __restrict__ cnt,
                                                          const int* __restrict__ bsum,
                                                          int* __restrict__ cursor, int N) {
    __shared__ int s[256];
    const int tid = threadIdx.x;
    const int i = blockIdx.x * 256 + tid;
    const int v = (i < N) ? cnt[i] : 0;
    s[tid] = v;
    __syncthreads();
    for (int d = 1; d < 256; d <<= 1) {
        const int t = (tid >= d) ? s[tid - d] : 0;
        __syncthreads();
        s[tid] += t;
        __syncthreads();
    }
    if (i < N) cursor[i] = bsum[blockIdx.x] + s[tid] - v;
}

// ---------------- XCD-partitioned CSR scatter, float4 payload ----------------
__global__ __launch_bounds__(256) void scatter_pack_kernel(
    const int* __restrict__ src, const int* __restrict__ dst,
    const float* __restrict__ ea,
    int* __restrict__ cursor, float4* __restrict__ spf, int E) {
    const int range = blockIdx.x & 7;
    const int lo = range * (N_NODES / 8);
    const int hi = lo + (N_NODES / 8);
    int i = (blockIdx.x >> 3) * blockDim.x + threadIdx.x;
    const int stride = (gridDim.x >> 3) * blockDim.x;
    for (; i < E; i += stride) {
        const int d = dst[i];
        if (d >= lo && d < hi) {
            const int pos = atomicAdd(&cursor[d], 1);
            spf[pos] = make_float4(__int_as_float(src[i]),
                                   ea[3 * (size_t)i + 0],
                                   ea[3 * (size_t)i + 1],
                                   ea[3 * (size_t)i + 2]);
        }
    }
}

// ---------------- fused layer 1: x-gather (L2-resident) + per-edge projection
// Wave = 1 node; quarter q owns edge j+q; lane p computes cols 4p..4p+3.
// Per edge: two uniform-within-quarter loads of the 32B x8 row (3.2MB table,
// L2-hit), 9 FMA per col in registers, relu, accumulate. Epilogue: t@W1b+b1b,
// relu, @W2a+b2a -> PH2 (half).
__global__ __launch_bounds__(256) void fused_l1x(
    const float* __restrict__ x8,    // [N,8] f32 padded
    const float4* __restrict__ spf,  // [E] CSR-ordered (src, ea0, ea1, ea2)
    const int* __restrict__ cursor, const int* __restrict__ cnt,
    const float* __restrict__ inv,
    const float* __restrict__ W1a,   // [9,64]
    const float* __restrict__ b1a,
    const float* __restrict__ W1b,   // [64,64]
    const float* __restrict__ b1b,
    const float* __restrict__ W2a,   // [67,64] rows 0..63 used
    const float* __restrict__ b2a,
    __half* __restrict__ PH2, int N) {
    const int lane = threadIdx.x & 63;
    const int w    = threadIdx.x >> 6;
    const int q    = lane >> 4;
    const int p    = lane & 15;
    const int n    = blockIdx.x * 4 + w;

    __shared__ __align__(16) float lrow[4][64];

    float wx[6][4], wee[3][4], pb[4];
#pragma unroll
    for (int c = 0; c < 4; ++c) {
        pb[c] = b1a[4 * p + c];
#pragma unroll
        for (int k = 0; k < 6; ++k) wx[k][c] = W1a[k * 64 + 4 * p + c];
#pragma unroll
        for (int k = 0; k < 3; ++k) wee[k][c] = W1a[(6 + k) * 64 + 4 * p + c];
    }

    const int end   = cursor[n];
    const int count = cnt[n];
    int j = end - count;
    const float s_inv = inv[n];
    const float mask  = (s_inv != 0.0f) ? 1.0f : 0.0f;

    float s0 = 0.f, s1 = 0.f, s2 = 0.f, s3 = 0.f;

#define GRPX(base, valid)                                                        \
    {                                                                            \
        const int ei = (base) + q;                                               \
        const float4 f = spf[ei < end ? ei : end - 1];                           \
        const float* xr = x8 + ((size_t)__float_as_int(f.x) << 3);               \
        const float4 xlo = *(const float4*)xr;                                   \
        const float2 xhi = *(const float2*)(xr + 4);                             \
        float h0 = pb[0], h1 = pb[1], h2 = pb[2], h3 = pb[3];                    \
        h0 = fmaf(xlo.x, wx[0][0], h0); h1 = fmaf(xlo.x, wx[0][1], h1);          \
        h2 = fmaf(xlo.x, wx[0][2], h2); h3 = fmaf(xlo.x, wx[0][3], h3);          \
        h0 = fmaf(xlo.y, wx[1][0], h0); h1 = fmaf(xlo.y, wx[1][1], h1);          \
        h2 = fmaf(xlo.y, wx[1][2], h2); h3 = fmaf(xlo.y, wx[1][3], h3);          \
        h0 = fmaf(xlo.z, wx[2][0], h0); h1 = fmaf(xlo.z, wx[2][1], h1);          \
        h2 = fmaf(xlo.z, wx[2][2], h2); h3 = fmaf(xlo.z, wx[2][3], h3);          \
        h0 = fmaf(xlo.w, wx[3][0], h0); h1 = fmaf(xlo.w, wx[3][1], h1);          \
        h2 = fmaf(xlo.w, wx[3][2], h2); h3 = fmaf(xlo.w, wx[3][3], h3);          \
        h0 = fmaf(xhi.x, wx[4][0], h0); h1 = fmaf(xhi.x, wx[4][1], h1);          \
        h2 = fmaf(xhi.x, wx[4][2], h2); h3 = fmaf(xhi.x, wx[4][3], h3);          \
        h0 = fmaf(xhi.y, wx[5][0], h0); h1 = fmaf(xhi.y, wx[5][1], h1);          \
        h2 = fmaf(xhi.y, wx[5][2], h2); h3 = fmaf(xhi.y, wx[5][3], h3);          \
        h0 = fmaf(f.y, wee[0][0], h0);  h1 = fmaf(f.y, wee[0][1], h1);           \
        h2 = fmaf(f.y, wee[0][2], h2);  h3 = fmaf(f.y, wee[0][3], h3);           \
        h0 = fmaf(f.z, wee[1][0], h0);  h1 = fmaf(f.z, wee[1][1], h1);           \
        h2 = fmaf(f.z, wee[1][2], h2);  h3 = fmaf(f.z, wee[1][3], h3);           \
        h0 = fmaf(f.w, wee[2][0], h0);  h1 = fmaf(f.w, wee[2][1], h1);           \
        h2 = fmaf(f.w, wee[2][2], h2);  h3 = fmaf(f.w, wee[2][3], h3);           \
        if (valid) {                                                             \
            s0 += fmaxf(h0, 0.f); s1 += fmaxf(h1, 0.f);                          \
            s2 += fmaxf(h2, 0.f); s3 += fmaxf(h3, 0.f);                          \
        }                                                                        \
    }

    for (; j + 8 <= end; j += 8) { GRPX(j, true) GRPX(j + 4, true) }
    if (j + 4 <= end) { GRPX(j, true) j += 4; }
    {
        const int rem = end - j;
        if (rem > 0) { GRPX(j, (q < rem)) }
    }
#undef GRPX

    // reduce across the 4 quarters (butterfly)
    s0 += __shfl_xor(s0, 16); s1 += __shfl_xor(s1, 16);
    s2 += __shfl_xor(s2, 16); s3 += __shfl_xor(s3, 16);
    s0 += __shfl_xor(s0, 32); s1 += __shfl_xor(s1, 32);
    s2 += __shfl_xor(s2, 32); s3 += __shfl_xor(s3, 32);

    if (lane < 16) {
        *(float4*)&lrow[w][4 * p] =
            make_float4(s0 * s_inv, s1 * s_inv, s2 * s_inv, s3 * s_inv);
    }
    __builtin_amdgcn_wave_barrier();

    float m = b1b[lane] * mask;
#pragma unroll
    for (int k = 0; k < 16; ++k) {
        const float4 r = *(const float4*)&lrow[w][4 * k];
        m = fmaf(r.x, W1b[(4 * k + 0) * 64 + lane], m);
        m = fmaf(r.y, W1b[(4 * k + 1) * 64 + lane], m);
        m = fmaf(r.z, W1b[(4 * k + 2) * 64 + lane], m);
        m = fmaf(r.w, W1b[(4 * k + 3) * 64 + lane], m);
    }
    m = fmaxf(m, 0.0f);
    __builtin_amdgcn_wave_barrier();
    lrow[w][lane] = m;
    __builtin_amdgcn_wave_barrier();
    float o = b2a[lane];
#pragma unroll
    for (int k = 0; k < 16; ++k) {
        const float4 r = *(const float4*)&lrow[w][4 * k];
        o = fmaf(r.x, W2a[(4 * k + 0) * 64 + lane], o);
        o = fmaf(r.y, W2a[(4 * k + 1) * 64 + lane], o);
        o = fmaf(r.z, W2a[(4 * k + 2) * 64 + lane], o);
        o = fmaf(r.w, W2a[(4 * k + 3) * 64 + lane], o);
    }
    PH2[(size_t)n * 64 + lane] = __float2half_rn(o);
}

// ---------------- fused layer, DIN=64 fp16, quarter-wave gather --------------
template <int DNEXT, bool OUTH>
__global__ __launch_bounds__(256) void fused_agg64(
    const __half* __restrict__ P,    // [N,64] half
    const float4* __restrict__ spf,  // [E] CSR-ordered (src, ea0, ea1, ea2)
    const int* __restrict__ cursor, const int* __restrict__ cnt,
    const float* __restrict__ inv,
    const float* __restrict__ We,    // [3,64]
    const float* __restrict__ Wb,    // [64,64]
    const float* __restrict__ bb,
    const float* __restrict__ Wn,    // [64,DNEXT]
    const float* __restrict__ bn,
    void* __restrict__ Poutv, int N) {
    const int lane = threadIdx.x & 63;
    const int w    = threadIdx.x >> 6;
    const int q    = lane >> 4;
    const int p    = lane & 15;
    const int n    = blockIdx.x * 4 + w;

    __shared__ __align__(16) float lrow[4][64];

    float we0[4], we1[4], we2[4];
#pragma unroll
    for (int k = 0; k < 4; ++k) {
        we0[k] = We[0 * 64 + 4 * p + k];
        we1[k] = We[1 * 64 + 4 * p + k];
        we2[k] = We[2 * 64 + 4 * p + k];
    }

    const int end   = cursor[n];
    const int count = cnt[n];
    int j = end - count;
    const float s_inv = inv[n];
    const float mask  = (s_inv != 0.0f) ? 1.0f : 0.0f;

    float s0 = 0.f, s1 = 0.f, s2 = 0.f, s3 = 0.f;

#define GRP4H(base, valid)                                                       \
    {                                                                            \
        const int ei = (base) + q;                                               \
        const float4 f = spf[ei < end ? ei : end - 1];                           \
        const ushort4 raw = *(const ushort4*)((const unsigned short*)P +         \
                            ((size_t)__float_as_int(f.x) << 6) + 4 * p);         \
        const float p0 = __half2float(__ushort_as_half(raw.x));                  \
        const float p1 = __half2float(__ushort_as_half(raw.y));                  \
        const float p2 = __half2float(__ushort_as_half(raw.z));                  \
        const float p3 = __half2float(__ushort_as_half(raw.w));                  \
        const float h0 = fmaxf(fmaf(f.w, we2[0], fmaf(f.z, we1[0], fmaf(f.y, we0[0], p0))), 0.f); \
        const float h1 = fmaxf(fmaf(f.w, we2[1], fmaf(f.z, we1[1], fmaf(f.y, we0[1], p1))), 0.f); \
        const float h2 = fmaxf(fmaf(f.w, we2[2], fmaf(f.z, we1[2], fmaf(f.y, we0[2], p2))), 0.f); \
        const float h3 = fmaxf(fmaf(f.w, we2[3], fmaf(f.z, we1[3], fmaf(f.y, we0[3], p3))), 0.f); \
        if (valid) { s0 += h0; s1 += h1; s2 += h2; s3 += h3; }                   \
    }

    for (; j + 8 <= end; j += 8) { GRP4H(j, true) GRP4H(j + 4, true) }
    if (j + 4 <= end) { GRP4H(j, true) j += 4; }
    {
        const int rem = end - j;
        if (rem > 0) { GRP4H(j, (q < rem)) }
    }
#undef GRP4H

    // reduce across the 4 quarters (butterfly)
    s0 += __shfl_xor(s0, 16); s1 += __shfl_xor(s1, 16);
    s2 += __shfl_xor(s2, 16); s3 += __shfl_xor(s3, 16);
    s0 += __shfl_xor(s0, 32); s1 += __shfl_xor(s1, 32);
    s2 += __shfl_xor(s2, 32); s3 += __shfl_xor(s3, 32);

    if (lane < 16) {
        *(float4*)&lrow[w][4 * p] =
            make_float4(s0 * s_inv, s1 * s_inv, s2 * s_inv, s3 * s_inv);
    }
    __builtin_amdgcn_wave_barrier();

    float m = bb[lane] * mask;
#pragma unroll
    for (int k = 0; k < 16; ++k) {
        const float4 r = *(const float4*)&lrow[w][4 * k];
        m = fmaf(r.x, Wb[(4 * k + 0) * 64 + lane], m);
        m = fmaf(r.y, Wb[(4 * k + 1) * 64 + lane], m);
        m = fmaf(r.z, Wb[(4 * k + 2) * 64 + lane], m);
        m = fmaf(r.w, Wb[(4 * k + 3) * 64 + lane], m);
    }
    m = fmaxf(m, 0.0f);
    __builtin_amdgcn_wave_barrier();
    lrow[w][lane] = m;
    __builtin_amdgcn_wave_barrier();
    const int c2 = lane % DNEXT;
    float o = bn[c2];
#pragma unroll
    for (int k = 0; k < 16; ++k) {
        const float4 r = *(const float4*)&lrow[w][4 * k];
        o = fmaf(r.x, Wn[(4 * k + 0) * DNEXT + c2], o);
        o = fmaf(r.y, Wn[(4 * k + 1) * DNEXT + c2], o);
        o = fmaf(r.z, Wn[(4 * k + 2) * DNEXT + c2], o);
        o = fmaf(r.w, Wn[(4 * k + 3) * DNEXT + c2], o);
    }
    if (lane < DNEXT) {
        if constexpr (OUTH)
            ((__half*)Poutv)[(size_t)n * DNEXT + lane] = __float2half_rn(o);
        else
            ((float*)Poutv)[(size_t)n * DNEXT + lane] = o;
    }
}

// ---------------- fused last layer, DIN=32 fp16 rows (64B gathers) -----------
__global__ __launch_bounds__(256) void fused_agg32h(
    const __half* __restrict__ P,    // [N,32] half
    const float4* __restrict__ spf,
    const int* __restrict__ cursor, const int* __restrict__ cnt,
    const float* __restrict__ inv,
    const float* __restrict__ We,    // [3,32]
    const float* __restrict__ Wb,    // [32,32]
    const float* __restrict__ bb,
    float* __restrict__ out, int N) {
    const int lane = threadIdx.x & 63;
    const int w    = threadIdx.x >> 6;
    const int q    = lane >> 4;
    const int p    = lane & 15;
    const int n    = blockIdx.x * 4 + w;

    __shared__ __align__(16) float lrow[4][32];

    float we0[2], we1[2], we2[2];
#pragma unroll
    for (int k = 0; k < 2; ++k) {
        we0[k] = We[0 * 32 + 2 * p + k];
        we1[k] = We[1 * 32 + 2 * p + k];
        we2[k] = We[2 * 32 + 2 * p + k];
    }

    const int end   = cursor[n];
    const int count = cnt[n];
    int j = end - count;
    const float s_inv = inv[n];
    const float mask  = (s_inv != 0.0f) ? 1.0f : 0.0f;

    float s0 = 0.f, s1 = 0.f;

#define GRP4F(base, valid)                                                       \
    {                                                                            \
        const int ei = (base) + q;                                               \
        const float4 f = spf[ei < end ? ei : end - 1];                           \
        const __half2 pr = *(const __half2*)((const __half*)P +                  \
                           ((size_t)__float_as_int(f.x) << 5) + 2 * p);          \
        const float2 pf = __half22float2(pr);                                    \
        const float h0 = fmaxf(fmaf(f.w, we2[0], fmaf(f.z, we1[0], fmaf(f.y, we0[0], pf.x))), 0.f); \
        const float h1 = fmaxf(fmaf(f.w, we2[1], fmaf(f.z, we1[1], fmaf(f.y, we0[1], pf.y))), 0.f); \
        if (valid) { s0 += h0; s1 += h1; }                                       \
    }

    for (; j + 8 <= end; j += 8) { GRP4F(j, true) GRP4F(j + 4, true) }
    if (j + 4 <= end) { GRP4F(j, true) j += 4; }
    {
        const int rem = end - j;
        if (rem > 0) { GRP4F(j, (q < rem)) }
    }
#undef GRP4F

    s0 += __shfl_xor(s0, 16); s1 += __shfl_xor(s1, 16);
    s0 += __shfl_xor(s0, 32); s1 += __shfl_xor(s1, 32);

    if (lane < 16) {
        *(float2*)&lrow[w][2 * p] = make_float2(s0 * s_inv, s1 * s_inv);
    }
    __builtin_amdgcn_wave_barrier();

    const int c = lane & 31;
    float m = bb[c] * mask;
#pragma unroll
    for (int k = 0; k < 8; ++k) {
        const float4 r = *(const float4*)&lrow[w][4 * k];
        m = fmaf(r.x, Wb[(4 * k + 0) * 32 + c], m);
        m = fmaf(r.y, Wb[(4 * k + 1) * 32 + c], m);
        m = fmaf(r.z, Wb[(4 * k + 2) * 32 + c], m);
        m = fmaf(r.w, Wb[(4 * k + 3) * 32 + c], m);
    }
    if (lane < 32) out[(size_t)n * 32 + c] = m;
}

extern "C" void kernel_launch(void* const* d_in, const int* in_sizes, int n_in,
                              void* d_out, int out_size, void* d_ws, size_t ws_size,
                              hipStream_t stream) {
    const float* x   = (const float*)d_in[0];
    const int*   ei  = (const int*)d_in[1];
    const float* ea  = (const float*)d_in[2];
    const float* W1a = (const float*)d_in[3];
    const float* b1a = (const float*)d_in[4];
    const float* W1b = (const float*)d_in[5];
    const float* b1b = (const float*)d_in[6];
    const float* W2a = (const float*)d_in[7];
    const float* b2a = (const float*)d_in[8];
    const float* W2b = (const float*)d_in[9];
    const float* b2b = (const float*)d_in[10];
    const float* W3a = (const float*)d_in[11];
    const float* b3a = (const float*)d_in[12];
    const float* W3b = (const float*)d_in[13];
    const float* b3b = (const float*)d_in[14];

    const int* src = ei;
    const int* dst = ei + N_EDGES;
    float* out = (float*)d_out;

    // workspace (byte offsets), total ~62 MB:
    // cnt 0x0 | inv 0x80000 | bsum 0x100000 | cursor 0x110000 |
    // spf(float4) 0x200000 (25.6MB) | x8(f32 [N,8]) 0x1B00000 (3.2MB) |
    // PH2(half) 0x2800000 (12.8MB) | P3h(half) 0x3500000 (6.4MB)
    char* ws = (char*)d_ws;
    int*    cnt    = (int*)(ws);
    float*  inv    = (float*)(ws + 0x80000);
    int*    bsum   = (int*)(ws + 0x100000);
    int*    cursor = (int*)(ws + 0x110000);
    float4* spf    = (float4*)(ws + 0x200000);
    float*  x8     = (float*)(ws + 0x1B00000);
    __half* PH2    = (__half*)(ws + 0x2800000);
    __half* P3h    = (__half*)(ws + 0x3500000);

    const int NBLK = (N_NODES + 255) / 256;  // 391

    // graph preprocessing (shared by all 3 layers)
    hipMemsetAsync(cnt, 0, N_NODES * sizeof(int), stream);
    degree_kernel<<<2048, 256, 0, stream>>>(dst, cnt, N_EDGES);
    inv_kernel<<<NBLK, 256, 0, stream>>>(cnt, inv, N_NODES);
    block_sum_kernel<<<NBLK, 256, 0, stream>>>(cnt, bsum, N_NODES);
    scan_bsum_kernel<<<1, 512, 0, stream>>>(bsum, NBLK);
    make_cursor_kernel<<<NBLK, 256, 0, stream>>>(cnt, bsum, cursor, N_NODES);
    scatter_pack_kernel<<<2048, 256, 0, stream>>>(src, dst, ea, cursor, spf, N_EDGES);
    pad_x_kernel<<<(2 * N_NODES + 255) / 256, 256, 0, stream>>>(x, x8, N_NODES);
    // cursor[n] = end offset of node n's CSR range

    // layer 1: gather x8 (L2-resident), per-edge 9->64 projection,
    //          epilogue W1b+b1b, relu, W2a+b2a -> PH2(half)
    fused_l1x<<<N_NODES / 4, 256, 0, stream>>>(
        x8, spf, cursor, cnt, inv, W1a, b1a, W1b, b1b, W2a, b2a, PH2, N_NODES);
    // layer 2: gather PH2(half), epilogue W2b+b2b, relu, W3a+b3a -> P3h(half,[N,32])
    fused_agg64<32, true><<<N_NODES / 4, 256, 0, stream>>>(
        PH2, spf, cursor, cnt, inv, W2a + 64 * 64, W2b, b2b, W3a, b3a, P3h, N_NODES);
    // layer 3: gather P3h(half, 32-wide = 64B rows), final W3b+b3b -> out
    fused_agg32h<<<N_NODES / 4, 256, 0, stream>>>(
        P3h, spf, cursor, cnt, inv, W3a + 64 * 32, W3b, b3b, out, N_NODES);
}

// Round 11
// 473.738 us; speedup vs baseline: 1.0729x; 1.0729x over previous
//
#include <hip/hip_runtime.h>
#include <hip/hip_fp16.h>

#define N_NODES 100000
#define N_EDGES 1600000

// ---------------- degree (XCD-partitioned) ----------------
__global__ __launch_bounds__(256) void degree_kernel(const int* __restrict__ dst,
                                                     int* __restrict__ cnt, int E) {
    const int range = blockIdx.x & 7;
    const int lo = range * (N_NODES / 8);
    const int hi = lo + (N_NODES / 8);
    int i = (blockIdx.x >> 3) * blockDim.x + threadIdx.x;
    const int stride = (gridDim.x >> 3) * blockDim.x;
    for (; i < E; i += stride) {
        const int d = dst[i];
        if (d >= lo && d < hi) atomicAdd(&cnt[d], 1);
    }
}

__global__ __launch_bounds__(256) void inv_kernel(const int* __restrict__ cnt,
                                                  float* __restrict__ inv, int N) {
    int i = blockIdx.x * blockDim.x + threadIdx.x;
    if (i < N) inv[i] = (cnt[i] > 0) ? (1.0f / (float)cnt[i]) : 0.0f;
}

// ---------------- hierarchical exclusive scan (cnt -> cursor) ----------------
__global__ __launch_bounds__(256) void block_sum_kernel(const int* __restrict__ cnt,
                                                        int* __restrict__ bsum, int N) {
    __shared__ int s[256];
    const int tid = threadIdx.x;
    const int i = blockIdx.x * 256 + tid;
    s[tid] = (i < N) ? cnt[i] : 0;
    __syncthreads();
#pragma unroll
    for (int d = 128; d > 0; d >>= 1) {
        if (tid < d) s[tid] += s[tid + d];
        __syncthreads();
    }
    if (tid == 0) bsum[blockIdx.x] = s[0];
}

__global__ __launch_bounds__(512) void scan_bsum_kernel(int* __restrict__ bsum, int NB) {
    __shared__ int s[512];
    const int tid = threadIdx.x;
    const int v = (tid < NB) ? bsum[tid] : 0;
    s[tid] = v;
    __syncthreads();
    for (int d = 1; d < 512; d <<= 1) {
        const int t = (tid >= d) ? s[tid - d] : 0;
        __syncthreads();
        s[tid] += t;
        __syncthreads();
    }
    if (tid < NB) bsum[tid] = s[tid] - v;  // exclusive
}

__global__ __launch_bounds__(256) void make_cursor_kernel(const int* __restrict__ cnt,
                                                          const int* __restrict__ bsum,
                                                          int* __restrict__ cursor, int N) {
    __shared__ int s[256];
    const int tid = threadIdx.x;
    const int i = blockIdx.x * 256 + tid;
    const int v = (i < N) ? cnt[i] : 0;
    s[tid] = v;
    __syncthreads();
    for (int d = 1; d < 256; d <<= 1) {
        const int t = (tid >= d) ? s[tid - d] : 0;
        __syncthreads();
        s[tid] += t;
        __syncthreads();
    }
    if (i < N) cursor[i] = bsum[blockIdx.x] + s[tid] - v;
}

// ---------------- XCD-partitioned CSR scatter, float4 payload ----------------
__global__ __launch_bounds__(256) void scatter_pack_kernel(
    const int* __restrict__ src, const int* __restrict__ dst,
    const float* __restrict__ ea,
    int* __restrict__ cursor, float4* __restrict__ spf, int E) {
    const int range = blockIdx.x & 7;
    const int lo = range * (N_NODES / 8);
    const int hi = lo + (N_NODES / 8);
    int i = (blockIdx.x >> 3) * blockDim.x + threadIdx.x;
    const int stride = (gridDim.x >> 3) * blockDim.x;
    for (; i < E; i += stride) {
        const int d = dst[i];
        if (d >= lo && d < hi) {
            const int pos = atomicAdd(&cursor[d], 1);
            spf[pos] = make_float4(__int_as_float(src[i]),
                                   ea[3 * (size_t)i + 0],
                                   ea[3 * (size_t)i + 1],
                                   ea[3 * (size_t)i + 2]);
        }
    }
}

// ---------------- node GEMM: P1(half) = x @ W1a[0:6] + b1a ----------------
__global__ __launch_bounds__(256) void node_gemm6h(
    const float* __restrict__ x, const float* __restrict__ W,
    const float* __restrict__ bias, __half* __restrict__ out_, int N) {
    int n = blockIdx.x * blockDim.x + threadIdx.x;
    if (n >= N) return;
    const float* row = x + (size_t)n * 6;
    float v[6];
#pragma unroll
    for (int k = 0; k < 6; ++k) v[k] = row[k];
    __half2* orow = (__half2*)(out_ + (size_t)n * 64);
    for (int g = 0; g < 16; ++g) {
        float a0 = bias[4 * g + 0], a1 = bias[4 * g + 1];
        float a2 = bias[4 * g + 2], a3 = bias[4 * g + 3];
#pragma unroll
        for (int k = 0; k < 6; ++k) {
            const float m = v[k];
            const float* w = &W[k * 64 + 4 * g];
            a0 = fmaf(m, w[0], a0);
            a1 = fmaf(m, w[1], a1);
            a2 = fmaf(m, w[2], a2);
            a3 = fmaf(m, w[3], a3);
        }
        orow[2 * g]     = __floats2half2_rn(a0, a1);
        orow[2 * g + 1] = __floats2half2_rn(a2, a3);
    }
}

// ---------------- fused layer, DIN=64 fp16, 8-lane-subgroup gather -----------
// Wave = 1 node. Subgroup s (8 lanes, s=lane>>3) owns edge j+s; lane p=lane&7
// holds cols 8p..8p+7 (half8 = 16B load -> 8 lanes cover the 128B row).
// One gather instruction covers 8 edges (1KB); unroll 2 -> 16 rows in flight.
// Reduce across subgroups via __shfl_xor(8|16|32).
template <int DNEXT, bool OUTH>
__global__ __launch_bounds__(256) void fused_agg64(
    const __half* __restrict__ P,    // [N,64] half
    const float4* __restrict__ spf,  // [E] CSR-ordered (src, ea0, ea1, ea2)
    const int* __restrict__ cursor, const int* __restrict__ cnt,
    const float* __restrict__ inv,
    const float* __restrict__ We,    // [3,64]
    const float* __restrict__ Wb,    // [64,64]
    const float* __restrict__ bb,
    const float* __restrict__ Wn,    // [64,DNEXT]
    const float* __restrict__ bn,
    void* __restrict__ Poutv, int N) {
    const int lane = threadIdx.x & 63;
    const int w    = threadIdx.x >> 6;
    const int sub  = lane >> 3;   // 0..7 subgroup = edge slot
    const int p    = lane & 7;    // 0..7 column block
    const int n    = blockIdx.x * 4 + w;

    __shared__ __align__(16) float lrow[4][64];

    float we0[8], we1[8], we2[8];
#pragma unroll
    for (int k = 0; k < 8; ++k) {
        we0[k] = We[0 * 64 + 8 * p + k];
        we1[k] = We[1 * 64 + 8 * p + k];
        we2[k] = We[2 * 64 + 8 * p + k];
    }

    const int end   = cursor[n];
    const int count = cnt[n];
    int j = end - count;
    const float s_inv = inv[n];
    const float mask  = (s_inv != 0.0f) ? 1.0f : 0.0f;

    float s0 = 0.f, s1 = 0.f, s2 = 0.f, s3 = 0.f;
    float s4 = 0.f, s5 = 0.f, s6 = 0.f, s7 = 0.f;

#define GRP8(base, valid)                                                        \
    {                                                                            \
        const int ei = (base) + sub;                                             \
        const float4 f = spf[ei < end ? ei : end - 1];                           \
        const float4 rawf = *(const float4*)((const __half*)P +                  \
                            ((size_t)__float_as_int(f.x) << 6) + 8 * p);         \
        const __half2* hp = (const __half2*)&rawf;                               \
        const float2 q0 = __half22float2(hp[0]);                                 \
        const float2 q1 = __half22float2(hp[1]);                                 \
        const float2 q2 = __half22float2(hp[2]);                                 \
        const float2 q3 = __half22float2(hp[3]);                                 \
        const float h0 = fmaxf(fmaf(f.w, we2[0], fmaf(f.z, we1[0], fmaf(f.y, we0[0], q0.x))), 0.f); \
        const float h1 = fmaxf(fmaf(f.w, we2[1], fmaf(f.z, we1[1], fmaf(f.y, we0[1], q0.y))), 0.f); \
        const float h2 = fmaxf(fmaf(f.w, we2[2], fmaf(f.z, we1[2], fmaf(f.y, we0[2], q1.x))), 0.f); \
        const float h3 = fmaxf(fmaf(f.w, we2[3], fmaf(f.z, we1[3], fmaf(f.y, we0[3], q1.y))), 0.f); \
        const float h4 = fmaxf(fmaf(f.w, we2[4], fmaf(f.z, we1[4], fmaf(f.y, we0[4], q2.x))), 0.f); \
        const float h5 = fmaxf(fmaf(f.w, we2[5], fmaf(f.z, we1[5], fmaf(f.y, we0[5], q2.y))), 0.f); \
        const float h6 = fmaxf(fmaf(f.w, we2[6], fmaf(f.z, we1[6], fmaf(f.y, we0[6], q3.x))), 0.f); \
        const float h7 = fmaxf(fmaf(f.w, we2[7], fmaf(f.z, we1[7], fmaf(f.y, we0[7], q3.y))), 0.f); \
        if (valid) {                                                             \
            s0 += h0; s1 += h1; s2 += h2; s3 += h3;                              \
            s4 += h4; s5 += h5; s6 += h6; s7 += h7;                              \
        }                                                                        \
    }

    for (; j + 16 <= end; j += 16) { GRP8(j, true) GRP8(j + 8, true) }
    if (j + 8 <= end) { GRP8(j, true) j += 8; }
    {
        const int rem = end - j;
        if (rem > 0) { GRP8(j, (sub < rem)) }
    }
#undef GRP8

    // reduce across the 8 subgroups (butterfly)
#define RED(d) \
    s0 += __shfl_xor(s0, d); s1 += __shfl_xor(s1, d); \
    s2 += __shfl_xor(s2, d); s3 += __shfl_xor(s3, d); \
    s4 += __shfl_xor(s4, d); s5 += __shfl_xor(s5, d); \
    s6 += __shfl_xor(s6, d); s7 += __shfl_xor(s7, d);
    RED(8) RED(16) RED(32)
#undef RED

    if (lane < 8) {
        *(float4*)&lrow[w][8 * p] =
            make_float4(s0 * s_inv, s1 * s_inv, s2 * s_inv, s3 * s_inv);
        *(float4*)&lrow[w][8 * p + 4] =
            make_float4(s4 * s_inv, s5 * s_inv, s6 * s_inv, s7 * s_inv);
    }
    __builtin_amdgcn_wave_barrier();

    float m = bb[lane] * mask;
#pragma unroll
    for (int k = 0; k < 16; ++k) {
        const float4 r = *(const float4*)&lrow[w][4 * k];
        m = fmaf(r.x, Wb[(4 * k + 0) * 64 + lane], m);
        m = fmaf(r.y, Wb[(4 * k + 1) * 64 + lane], m);
        m = fmaf(r.z, Wb[(4 * k + 2) * 64 + lane], m);
        m = fmaf(r.w, Wb[(4 * k + 3) * 64 + lane], m);
    }
    m = fmaxf(m, 0.0f);
    __builtin_amdgcn_wave_barrier();
    lrow[w][lane] = m;
    __builtin_amdgcn_wave_barrier();
    const int c2 = lane % DNEXT;
    float o = bn[c2];
#pragma unroll
    for (int k = 0; k < 16; ++k) {
        const float4 r = *(const float4*)&lrow[w][4 * k];
        o = fmaf(r.x, Wn[(4 * k + 0) * DNEXT + c2], o);
        o = fmaf(r.y, Wn[(4 * k + 1) * DNEXT + c2], o);
        o = fmaf(r.z, Wn[(4 * k + 2) * DNEXT + c2], o);
        o = fmaf(r.w, Wn[(4 * k + 3) * DNEXT + c2], o);
    }
    if (lane < DNEXT) {
        if constexpr (OUTH)
            ((__half*)Poutv)[(size_t)n * DNEXT + lane] = __float2half_rn(o);
        else
            ((float*)Poutv)[(size_t)n * DNEXT + lane] = o;
    }
}

// ---------------- fused last layer, DIN=32 fp16, 4-lane-subgroup gather ------
// Wave = 1 node. Subgroup s (4 lanes, s=lane>>2) owns edge j+s; lane p=lane&3
// holds cols 8p..8p+7 (half8 = 16B -> 4 lanes cover the 64B row). One gather
// instruction covers 16 edges. Final: out = t@Wb + bb*mask (no relu).
__global__ __launch_bounds__(256) void fused_agg32h(
    const __half* __restrict__ P,    // [N,32] half
    const float4* __restrict__ spf,
    const int* __restrict__ cursor, const int* __restrict__ cnt,
    const float* __restrict__ inv,
    const float* __restrict__ We,    // [3,32]
    const float* __restrict__ Wb,    // [32,32]
    const float* __restrict__ bb,
    float* __restrict__ out, int N) {
    const int lane = threadIdx.x & 63;
    const int w    = threadIdx.x >> 6;
    const int sub  = lane >> 2;   // 0..15 subgroup = edge slot
    const int p    = lane & 3;    // 0..3 column block
    const int n    = blockIdx.x * 4 + w;

    __shared__ __align__(16) float lrow[4][32];

    float we0[8], we1[8], we2[8];
#pragma unroll
    for (int k = 0; k < 8; ++k) {
        we0[k] = We[0 * 32 + 8 * p + k];
        we1[k] = We[1 * 32 + 8 * p + k];
        we2[k] = We[2 * 32 + 8 * p + k];
    }

    const int end   = cursor[n];
    const int count = cnt[n];
    int j = end - count;
    const float s_inv = inv[n];
    const float mask  = (s_inv != 0.0f) ? 1.0f : 0.0f;

    float s0 = 0.f, s1 = 0.f, s2 = 0.f, s3 = 0.f;
    float s4 = 0.f, s5 = 0.f, s6 = 0.f, s7 = 0.f;

#define GRP16(base, valid)                                                       \
    {                                                                            \
        const int ei = (base) + sub;                                             \
        const float4 f = spf[ei < end ? ei : end - 1];                           \
        const float4 rawf = *(const float4*)((const __half*)P +                  \
                            ((size_t)__float_as_int(f.x) << 5) + 8 * p);         \
        const __half2* hp = (const __half2*)&rawf;                               \
        const float2 q0 = __half22float2(hp[0]);                                 \
        const float2 q1 = __half22float2(hp[1]);                                 \
        const float2 q2 = __half22float2(hp[2]);                                 \
        const float2 q3 = __half22float2(hp[3]);                                 \
        const float h0 = fmaxf(fmaf(f.w, we2[0], fmaf(f.z, we1[0], fmaf(f.y, we0[0], q0.x))), 0.f); \
        const float h1 = fmaxf(fmaf(f.w, we2[1], fmaf(f.z, we1[1], fmaf(f.y, we0[1], q0.y))), 0.f); \
        const float h2 = fmaxf(fmaf(f.w, we2[2], fmaf(f.z, we1[2], fmaf(f.y, we0[2], q1.x))), 0.f); \
        const float h3 = fmaxf(fmaf(f.w, we2[3], fmaf(f.z, we1[3], fmaf(f.y, we0[3], q1.y))), 0.f); \
        const float h4 = fmaxf(fmaf(f.w, we2[4], fmaf(f.z, we1[4], fmaf(f.y, we0[4], q2.x))), 0.f); \
        const float h5 = fmaxf(fmaf(f.w, we2[5], fmaf(f.z, we1[5], fmaf(f.y, we0[5], q2.y))), 0.f); \
        const float h6 = fmaxf(fmaf(f.w, we2[6], fmaf(f.z, we1[6], fmaf(f.y, we0[6], q3.x))), 0.f); \
        const float h7 = fmaxf(fmaf(f.w, we2[7], fmaf(f.z, we1[7], fmaf(f.y, we0[7], q3.y))), 0.f); \
        if (valid) {                                                             \
            s0 += h0; s1 += h1; s2 += h2; s3 += h3;                              \
            s4 += h4; s5 += h5; s6 += h6; s7 += h7;                              \
        }                                                                        \
    }

    for (; j + 16 <= end; j += 16) { GRP16(j, true) }
    {
        const int rem = end - j;
        if (rem > 0) { GRP16(j, (sub < rem)) }
    }
#undef GRP16

#define RED(d) \
    s0 += __shfl_xor(s0, d); s1 += __shfl_xor(s1, d); \
    s2 += __shfl_xor(s2, d); s3 += __shfl_xor(s3, d); \
    s4 += __shfl_xor(s4, d); s5 += __shfl_xor(s5, d); \
    s6 += __shfl_xor(s6, d); s7 += __shfl_xor(s7, d);
    RED(4) RED(8) RED(16) RED(32)
#undef RED

    if (lane < 4) {
        *(float4*)&lrow[w][8 * p] =
            make_float4(s0 * s_inv, s1 * s_inv, s2 * s_inv, s3 * s_inv);
        *(float4*)&lrow[w][8 * p + 4] =
            make_float4(s4 * s_inv, s5 * s_inv, s6 * s_inv, s7 * s_inv);
    }
    __builtin_amdgcn_wave_barrier();

    const int c = lane & 31;
    float m = bb[c] * mask;
#pragma unroll
    for (int k = 0; k < 8; ++k) {
        const float4 r = *(const float4*)&lrow[w][4 * k];
        m = fmaf(r.x, Wb[(4 * k + 0) * 32 + c], m);
        m = fmaf(r.y, Wb[(4 * k + 1) * 32 + c], m);
        m = fmaf(r.z, Wb[(4 * k + 2) * 32 + c], m);
        m = fmaf(r.w, Wb[(4 * k + 3) * 32 + c], m);
    }
    if (lane < 32) out[(size_t)n * 32 + c] = m;
}

extern "C" void kernel_launch(void* const* d_in, const int* in_sizes, int n_in,
                              void* d_out, int out_size, void* d_ws, size_t ws_size,
                              hipStream_t stream) {
    const float* x   = (const float*)d_in[0];
    const int*   ei  = (const int*)d_in[1];
    const float* ea  = (const float*)d_in[2];
    const float* W1a = (const float*)d_in[3];
    const float* b1a = (const float*)d_in[4];
    const float* W1b = (const float*)d_in[5];
    const float* b1b = (const float*)d_in[6];
    const float* W2a = (const float*)d_in[7];
    const float* b2a = (const float*)d_in[8];
    const float* W2b = (const float*)d_in[9];
    const float* b2b = (const float*)d_in[10];
    const float* W3a = (const float*)d_in[11];
    const float* b3a = (const float*)d_in[12];
    const float* W3b = (const float*)d_in[13];
    const float* b3b = (const float*)d_in[14];

    const int* src = ei;
    const int* dst = ei + N_EDGES;
    float* out = (float*)d_out;

    // workspace (byte offsets), total ~62 MB:
    // cnt 0x0 | inv 0x80000 | bsum 0x100000 | cursor 0x110000 |
    // spf(float4) 0x200000 (25.6MB) | PH1(half) 0x1B00000 (12.8MB) |
    // PH2(half) 0x2800000 (12.8MB) | P3h(half) 0x3500000 (6.4MB)
    char* ws = (char*)d_ws;
    int*    cnt    = (int*)(ws);
    float*  inv    = (float*)(ws + 0x80000);
    int*    bsum   = (int*)(ws + 0x100000);
    int*    cursor = (int*)(ws + 0x110000);
    float4* spf    = (float4*)(ws + 0x200000);
    __half* PH1    = (__half*)(ws + 0x1B00000);
    __half* PH2    = (__half*)(ws + 0x2800000);
    __half* P3h    = (__half*)(ws + 0x3500000);

    const int NBLK = (N_NODES + 255) / 256;  // 391

    // graph preprocessing (shared by all 3 layers)
    hipMemsetAsync(cnt, 0, N_NODES * sizeof(int), stream);
    degree_kernel<<<2048, 256, 0, stream>>>(dst, cnt, N_EDGES);
    inv_kernel<<<NBLK, 256, 0, stream>>>(cnt, inv, N_NODES);
    block_sum_kernel<<<NBLK, 256, 0, stream>>>(cnt, bsum, N_NODES);
    scan_bsum_kernel<<<1, 512, 0, stream>>>(bsum, NBLK);
    make_cursor_kernel<<<NBLK, 256, 0, stream>>>(cnt, bsum, cursor, N_NODES);
    scatter_pack_kernel<<<2048, 256, 0, stream>>>(src, dst, ea, cursor, spf, N_EDGES);
    // cursor[n] = end offset of node n's CSR range

    // P1 = half(x @ W1a[0:6] + b1a)
    node_gemm6h<<<NBLK, 256, 0, stream>>>(x, W1a, b1a, PH1, N_NODES);

    // layer 1: gather PH1(half), epilogue W1b+b1b, relu, W2a+b2a -> PH2(half)
    fused_agg64<64, true><<<N_NODES / 4, 256, 0, stream>>>(
        PH1, spf, cursor, cnt, inv, W1a + 6 * 64, W1b, b1b, W2a, b2a, PH2, N_NODES);
    // layer 2: gather PH2(half), epilogue W2b+b2b, relu, W3a+b3a -> P3h(half,[N,32])
    fused_agg64<32, true><<<N_NODES / 4, 256, 0, stream>>>(
        PH2, spf, cursor, cnt, inv, W2a + 64 * 64, W2b, b2b, W3a, b3a, P3h, N_NODES);
    // layer 3: gather P3h(half, 32-wide = 64B rows), final W3b+b3b -> out
    fused_agg32h<<<N_NODES / 4, 256, 0, stream>>>(
        P3h, spf, cursor, cnt, inv, W3a + 64 * 32, W3b, b3b, out, N_NODES);
}

// Round 12
// 467.493 us; speedup vs baseline: 1.0872x; 1.0134x over previous
//
#include <hip/hip_runtime.h>
#include <hip/hip_fp16.h>

#define N_NODES 100000
#define N_EDGES 1600000

// ---------------- degree (XCD-partitioned) ----------------
__global__ __launch_bounds__(256) void degree_kernel(const int* __restrict__ dst,
                                                     int* __restrict__ cnt, int E) {
    const int range = blockIdx.x & 7;
    const int lo = range * (N_NODES / 8);
    const int hi = lo + (N_NODES / 8);
    int i = (blockIdx.x >> 3) * blockDim.x + threadIdx.x;
    const int stride = (gridDim.x >> 3) * blockDim.x;
    for (; i < E; i += stride) {
        const int d = dst[i];
        if (d >= lo && d < hi) atomicAdd(&cnt[d], 1);
    }
}

__global__ __launch_bounds__(256) void inv_kernel(const int* __restrict__ cnt,
                                                  float* __restrict__ inv, int N) {
    int i = blockIdx.x * blockDim.x + threadIdx.x;
    if (i < N) inv[i] = (cnt[i] > 0) ? (1.0f / (float)cnt[i]) : 0.0f;
}

// ---------------- hierarchical exclusive scan (cnt -> cursor) ----------------
__global__ __launch_bounds__(256) void block_sum_kernel(const int* __restrict__ cnt,
                                                        int* __restrict__ bsum, int N) {
    __shared__ int s[256];
    const int tid = threadIdx.x;
    const int i = blockIdx.x * 256 + tid;
    s[tid] = (i < N) ? cnt[i] : 0;
    __syncthreads();
#pragma unroll
    for (int d = 128; d > 0; d >>= 1) {
        if (tid < d) s[tid] += s[tid + d];
        __syncthreads();
    }
    if (tid == 0) bsum[blockIdx.x] = s[0];
}

__global__ __launch_bounds__(512) void scan_bsum_kernel(int* __restrict__ bsum, int NB) {
    __shared__ int s[512];
    const int tid = threadIdx.x;
    const int v = (tid < NB) ? bsum[tid] : 0;
    s[tid] = v;
    __syncthreads();
    for (int d = 1; d < 512; d <<= 1) {
        const int t = (tid >= d) ? s[tid - d] : 0;
        __syncthreads();
        s[tid] += t;
        __syncthreads();
    }
    if (tid < NB) bsum[tid] = s[tid] - v;  // exclusive
}

__global__ __launch_bounds__(256) void make_cursor_kernel(const int* __restrict__ cnt,
                                                          const int* __restrict__ bsum,
                                                          int* __restrict__ cursor, int N) {
    __shared__ int s[256];
    const int tid = threadIdx.x;
    const int i = blockIdx.x * 256 + tid;
    const int v = (i < N) ? cnt[i] : 0;
    s[tid] = v;
    __syncthreads();
    for (int d = 1; d < 256; d <<= 1) {
        const int t = (tid >= d) ? s[tid - d] : 0;
        __syncthreads();
        s[tid] += t;
        __syncthreads();
    }
    if (i < N) cursor[i] = bsum[blockIdx.x] + s[tid] - v;
}

// ---------------- XCD-partitioned CSR scatter, float4 payload ----------------
__global__ __launch_bounds__(256) void scatter_pack_kernel(
    const int* __restrict__ src, const int* __restrict__ dst,
    const float* __restrict__ ea,
    int* __restrict__ cursor, float4* __restrict__ spf, int E) {
    const int range = blockIdx.x & 7;
    const int lo = range * (N_NODES / 8);
    const int hi = lo + (N_NODES / 8);
    int i = (blockIdx.x >> 3) * blockDim.x + threadIdx.x;
    const int stride = (gridDim.x >> 3) * blockDim.x;
    for (; i < E; i += stride) {
        const int d = dst[i];
        if (d >= lo && d < hi) {
            const int pos = atomicAdd(&cursor[d], 1);
            spf[pos] = make_float4(__int_as_float(src[i]),
                                   ea[3 * (size_t)i + 0],
                                   ea[3 * (size_t)i + 1],
                                   ea[3 * (size_t)i + 2]);
        }
    }
}

// ---------------- node GEMM: P1(half) = x @ W1a[0:6] + b1a ----------------
__global__ __launch_bounds__(256) void node_gemm6h(
    const float* __restrict__ x, const float* __restrict__ W,
    const float* __restrict__ bias, __half* __restrict__ out_, int N) {
    int n = blockIdx.x * blockDim.x + threadIdx.x;
    if (n >= N) return;
    const float* row = x + (size_t)n * 6;
    float v[6];
#pragma unroll
    for (int k = 0; k < 6; ++k) v[k] = row[k];
    __half2* orow = (__half2*)(out_ + (size_t)n * 64);
    for (int g = 0; g < 16; ++g) {
        float a0 = bias[4 * g + 0], a1 = bias[4 * g + 1];
        float a2 = bias[4 * g + 2], a3 = bias[4 * g + 3];
#pragma unroll
        for (int k = 0; k < 6; ++k) {
            const float m = v[k];
            const float* w = &W[k * 64 + 4 * g];
            a0 = fmaf(m, w[0], a0);
            a1 = fmaf(m, w[1], a1);
            a2 = fmaf(m, w[2], a2);
            a3 = fmaf(m, w[3], a3);
        }
        orow[2 * g]     = __floats2half2_rn(a0, a1);
        orow[2 * g + 1] = __floats2half2_rn(a2, a3);
    }
}

// ---------------- PURE aggregate, DIN=64 fp16, 8-lane-subgroup gather --------
// Grid-stride wave-per-node loop (We regs amortized over ~25 nodes/wave).
// A[n,c] = inv[n] * sum_e relu(P[src_e,c] + ea_e @ We[:,c]).  No epilogue.
__global__ __launch_bounds__(256) void agg64_pure(
    const __half* __restrict__ P,    // [N,64] half
    const float4* __restrict__ spf,  // [E] CSR-ordered (src, ea0, ea1, ea2)
    const int* __restrict__ cursor, const int* __restrict__ cnt,
    const float* __restrict__ inv,
    const float* __restrict__ We,    // [3,64]
    __half* __restrict__ A, int N) {
    const int lane  = threadIdx.x & 63;
    const int sub   = lane >> 3;   // 0..7 subgroup = edge slot
    const int p     = lane & 7;    // 0..7 column block (8 cols)
    const int gw    = (blockIdx.x * blockDim.x + threadIdx.x) >> 6;
    const int nwave = (gridDim.x * blockDim.x) >> 6;

    float we0[8], we1[8], we2[8];
#pragma unroll
    for (int k = 0; k < 8; ++k) {
        we0[k] = We[0 * 64 + 8 * p + k];
        we1[k] = We[1 * 64 + 8 * p + k];
        we2[k] = We[2 * 64 + 8 * p + k];
    }

    for (int n = gw; n < N; n += nwave) {
        const int end   = cursor[n];
        const int count = cnt[n];
        int j = end - count;
        const float s_inv = inv[n];

        float s0 = 0.f, s1 = 0.f, s2 = 0.f, s3 = 0.f;
        float s4 = 0.f, s5 = 0.f, s6 = 0.f, s7 = 0.f;

#define GRP8(base, valid)                                                        \
    {                                                                            \
        const int ei = (base) + sub;                                             \
        const float4 f = spf[ei < end ? ei : end - 1];                           \
        const float4 rawf = *(const float4*)((const __half*)P +                  \
                            ((size_t)__float_as_int(f.x) << 6) + 8 * p);         \
        const __half2* hp = (const __half2*)&rawf;                               \
        const float2 q0 = __half22float2(hp[0]);                                 \
        const float2 q1 = __half22float2(hp[1]);                                 \
        const float2 q2 = __half22float2(hp[2]);                                 \
        const float2 q3 = __half22float2(hp[3]);                                 \
        const float h0 = fmaxf(fmaf(f.w, we2[0], fmaf(f.z, we1[0], fmaf(f.y, we0[0], q0.x))), 0.f); \
        const float h1 = fmaxf(fmaf(f.w, we2[1], fmaf(f.z, we1[1], fmaf(f.y, we0[1], q0.y))), 0.f); \
        const float h2 = fmaxf(fmaf(f.w, we2[2], fmaf(f.z, we1[2], fmaf(f.y, we0[2], q1.x))), 0.f); \
        const float h3 = fmaxf(fmaf(f.w, we2[3], fmaf(f.z, we1[3], fmaf(f.y, we0[3], q1.y))), 0.f); \
        const float h4 = fmaxf(fmaf(f.w, we2[4], fmaf(f.z, we1[4], fmaf(f.y, we0[4], q2.x))), 0.f); \
        const float h5 = fmaxf(fmaf(f.w, we2[5], fmaf(f.z, we1[5], fmaf(f.y, we0[5], q2.y))), 0.f); \
        const float h6 = fmaxf(fmaf(f.w, we2[6], fmaf(f.z, we1[6], fmaf(f.y, we0[6], q3.x))), 0.f); \
        const float h7 = fmaxf(fmaf(f.w, we2[7], fmaf(f.z, we1[7], fmaf(f.y, we0[7], q3.y))), 0.f); \
        if (valid) {                                                             \
            s0 += h0; s1 += h1; s2 += h2; s3 += h3;                              \
            s4 += h4; s5 += h5; s6 += h6; s7 += h7;                              \
        }                                                                        \
    }

        for (; j + 16 <= end; j += 16) { GRP8(j, true) GRP8(j + 8, true) }
        if (j + 8 <= end) { GRP8(j, true) j += 8; }
        {
            const int rem = end - j;
            if (rem > 0) { GRP8(j, (sub < rem)) }
        }
#undef GRP8

#define RED(d) \
        s0 += __shfl_xor(s0, d); s1 += __shfl_xor(s1, d); \
        s2 += __shfl_xor(s2, d); s3 += __shfl_xor(s3, d); \
        s4 += __shfl_xor(s4, d); s5 += __shfl_xor(s5, d); \
        s6 += __shfl_xor(s6, d); s7 += __shfl_xor(s7, d);
        RED(8) RED(16) RED(32)
#undef RED

        if (lane < 8) {
            __half2 h01 = __floats2half2_rn(s0 * s_inv, s1 * s_inv);
            __half2 h23 = __floats2half2_rn(s2 * s_inv, s3 * s_inv);
            __half2 h45 = __floats2half2_rn(s4 * s_inv, s5 * s_inv);
            __half2 h67 = __floats2half2_rn(s6 * s_inv, s7 * s_inv);
            union { __half2 h[4]; float4 f; } u;
            u.h[0] = h01; u.h[1] = h23; u.h[2] = h45; u.h[3] = h67;
            *(float4*)(A + (size_t)n * 64 + 8 * p) = u.f;
        }
    }
}

// ---------------- PURE aggregate, DIN=32 fp16, 4-lane-subgroup gather --------
__global__ __launch_bounds__(256) void agg32_pure(
    const __half* __restrict__ P,    // [N,32] half
    const float4* __restrict__ spf,
    const int* __restrict__ cursor, const int* __restrict__ cnt,
    const float* __restrict__ inv,
    const float* __restrict__ We,    // [3,32]
    __half* __restrict__ A, int N) {
    const int lane  = threadIdx.x & 63;
    const int sub   = lane >> 2;   // 0..15 subgroup = edge slot
    const int p     = lane & 3;    // 0..3 column block (8 cols)
    const int gw    = (blockIdx.x * blockDim.x + threadIdx.x) >> 6;
    const int nwave = (gridDim.x * blockDim.x) >> 6;

    float we0[8], we1[8], we2[8];
#pragma unroll
    for (int k = 0; k < 8; ++k) {
        we0[k] = We[0 * 32 + 8 * p + k];
        we1[k] = We[1 * 32 + 8 * p + k];
        we2[k] = We[2 * 32 + 8 * p + k];
    }

    for (int n = gw; n < N; n += nwave) {
        const int end   = cursor[n];
        const int count = cnt[n];
        int j = end - count;
        const float s_inv = inv[n];

        float s0 = 0.f, s1 = 0.f, s2 = 0.f, s3 = 0.f;
        float s4 = 0.f, s5 = 0.f, s6 = 0.f, s7 = 0.f;

#define GRP16(base, valid)                                                       \
    {                                                                            \
        const int ei = (base) + sub;                                             \
        const float4 f = spf[ei < end ? ei : end - 1];                           \
        const float4 rawf = *(const float4*)((const __half*)P +                  \
                            ((size_t)__float_as_int(f.x) << 5) + 8 * p);         \
        const __half2* hp = (const __half2*)&rawf;                               \
        const float2 q0 = __half22float2(hp[0]);                                 \
        const float2 q1 = __half22float2(hp[1]);                                 \
        const float2 q2 = __half22float2(hp[2]);                                 \
        const float2 q3 = __half22float2(hp[3]);                                 \
        const float h0 = fmaxf(fmaf(f.w, we2[0], fmaf(f.z, we1[0], fmaf(f.y, we0[0], q0.x))), 0.f); \
        const float h1 = fmaxf(fmaf(f.w, we2[1], fmaf(f.z, we1[1], fmaf(f.y, we0[1], q0.y))), 0.f); \
        const float h2 = fmaxf(fmaf(f.w, we2[2], fmaf(f.z, we1[2], fmaf(f.y, we0[2], q1.x))), 0.f); \
        const float h3 = fmaxf(fmaf(f.w, we2[3], fmaf(f.z, we1[3], fmaf(f.y, we0[3], q1.y))), 0.f); \
        const float h4 = fmaxf(fmaf(f.w, we2[4], fmaf(f.z, we1[4], fmaf(f.y, we0[4], q2.x))), 0.f); \
        const float h5 = fmaxf(fmaf(f.w, we2[5], fmaf(f.z, we1[5], fmaf(f.y, we0[5], q2.y))), 0.f); \
        const float h6 = fmaxf(fmaf(f.w, we2[6], fmaf(f.z, we1[6], fmaf(f.y, we0[6], q3.x))), 0.f); \
        const float h7 = fmaxf(fmaf(f.w, we2[7], fmaf(f.z, we1[7], fmaf(f.y, we0[7], q3.y))), 0.f); \
        if (valid) {                                                             \
            s0 += h0; s1 += h1; s2 += h2; s3 += h3;                              \
            s4 += h4; s5 += h5; s6 += h6; s7 += h7;                              \
        }                                                                        \
    }

        for (; j + 16 <= end; j += 16) { GRP16(j, true) }
        {
            const int rem = end - j;
            if (rem > 0) { GRP16(j, (sub < rem)) }
        }
#undef GRP16

#define RED(d) \
        s0 += __shfl_xor(s0, d); s1 += __shfl_xor(s1, d); \
        s2 += __shfl_xor(s2, d); s3 += __shfl_xor(s3, d); \
        s4 += __shfl_xor(s4, d); s5 += __shfl_xor(s5, d); \
        s6 += __shfl_xor(s6, d); s7 += __shfl_xor(s7, d);
        RED(4) RED(8) RED(16) RED(32)
#undef RED

        if (lane < 4) {
            __half2 h01 = __floats2half2_rn(s0 * s_inv, s1 * s_inv);
            __half2 h23 = __floats2half2_rn(s2 * s_inv, s3 * s_inv);
            __half2 h45 = __floats2half2_rn(s4 * s_inv, s5 * s_inv);
            __half2 h67 = __floats2half2_rn(s6 * s_inv, s7 * s_inv);
            union { __half2 h[4]; float4 f; } u;
            u.h[0] = h01; u.h[1] = h23; u.h[2] = h45; u.h[3] = h67;
            *(float4*)(A + (size_t)n * 32 + 8 * p) = u.f;
        }
    }
}

// ---------------- node MLP: thread-per-node, s_load weights ------------------
// out[n] = act(in[n] @ W + b * bs), fp16 in / fp16 out.
// MASK: bs = (inv[n]!=0), RELU: relu after bias.
template <int IN, int OUT, bool RELU, bool MASK>
__global__ __launch_bounds__(256) void node_mlp_h(
    const __half* __restrict__ in_, const float* __restrict__ W,
    const float* __restrict__ bias, const float* __restrict__ inv,
    __half* __restrict__ out_, int N) {
    int n = blockIdx.x * blockDim.x + threadIdx.x;
    if (n >= N) return;
    const __half* row = in_ + (size_t)n * IN;
    float v[IN];
#pragma unroll
    for (int q = 0; q < IN / 8; ++q) {
        float4 raw = ((const float4*)row)[q];
        const __half2* hp = (const __half2*)&raw;
#pragma unroll
        for (int t = 0; t < 4; ++t) {
            const float2 f2 = __half22float2(hp[t]);
            v[8 * q + 2 * t]     = f2.x;
            v[8 * q + 2 * t + 1] = f2.y;
        }
    }
    float bs = 1.0f;
    if constexpr (MASK) bs = (inv[n] != 0.0f) ? 1.0f : 0.0f;

    __half2 hout[OUT / 2];
    for (int g = 0; g < OUT / 4; ++g) {   // rolled: weights via uniform s_load
        float a0 = bias[4 * g + 0] * bs, a1 = bias[4 * g + 1] * bs;
        float a2 = bias[4 * g + 2] * bs, a3 = bias[4 * g + 3] * bs;
#pragma unroll
        for (int k = 0; k < IN; ++k) {
            const float m = v[k];
            const float* w = &W[k * OUT + 4 * g];
            a0 = fmaf(m, w[0], a0);
            a1 = fmaf(m, w[1], a1);
            a2 = fmaf(m, w[2], a2);
            a3 = fmaf(m, w[3], a3);
        }
        if (RELU) {
            a0 = fmaxf(a0, 0.f); a1 = fmaxf(a1, 0.f);
            a2 = fmaxf(a2, 0.f); a3 = fmaxf(a3, 0.f);
        }
        hout[2 * g]     = __floats2half2_rn(a0, a1);
        hout[2 * g + 1] = __floats2half2_rn(a2, a3);
    }
    float4* orow = (float4*)(out_ + (size_t)n * OUT);
#pragma unroll
    for (int q = 0; q < OUT / 8; ++q) orow[q] = ((const float4*)hout)[q];
}

// final: fp16 in -> fp32 out, masked bias, no relu
__global__ __launch_bounds__(256) void node_mlp_final(
    const __half* __restrict__ in_, const float* __restrict__ W,
    const float* __restrict__ bias, const float* __restrict__ inv,
    float* __restrict__ out_, int N) {
    int n = blockIdx.x * blockDim.x + threadIdx.x;
    if (n >= N) return;
    const __half* row = in_ + (size_t)n * 32;
    float v[32];
#pragma unroll
    for (int q = 0; q < 4; ++q) {
        float4 raw = ((const float4*)row)[q];
        const __half2* hp = (const __half2*)&raw;
#pragma unroll
        for (int t = 0; t < 4; ++t) {
            const float2 f2 = __half22float2(hp[t]);
            v[8 * q + 2 * t]     = f2.x;
            v[8 * q + 2 * t + 1] = f2.y;
        }
    }
    const float bs = (inv[n] != 0.0f) ? 1.0f : 0.0f;
    float* orow = out_ + (size_t)n * 32;
    for (int g = 0; g < 8; ++g) {
        float a0 = bias[4 * g + 0] * bs, a1 = bias[4 * g + 1] * bs;
        float a2 = bias[4 * g + 2] * bs, a3 = bias[4 * g + 3] * bs;
#pragma unroll
        for (int k = 0; k < 32; ++k) {
            const float m = v[k];
            const float* w = &W[k * 32 + 4 * g];
            a0 = fmaf(m, w[0], a0);
            a1 = fmaf(m, w[1], a1);
            a2 = fmaf(m, w[2], a2);
            a3 = fmaf(m, w[3], a3);
        }
        ((float4*)orow)[g] = make_float4(a0, a1, a2, a3);
    }
}

extern "C" void kernel_launch(void* const* d_in, const int* in_sizes, int n_in,
                              void* d_out, int out_size, void* d_ws, size_t ws_size,
                              hipStream_t stream) {
    const float* x   = (const float*)d_in[0];
    const int*   ei  = (const int*)d_in[1];
    const float* ea  = (const float*)d_in[2];
    const float* W1a = (const float*)d_in[3];
    const float* b1a = (const float*)d_in[4];
    const float* W1b = (const float*)d_in[5];
    const float* b1b = (const float*)d_in[6];
    const float* W2a = (const float*)d_in[7];
    const float* b2a = (const float*)d_in[8];
    const float* W2b = (const float*)d_in[9];
    const float* b2b = (const float*)d_in[10];
    const float* W3a = (const float*)d_in[11];
    const float* b3a = (const float*)d_in[12];
    const float* W3b = (const float*)d_in[13];
    const float* b3b = (const float*)d_in[14];

    const int* src = ei;
    const int* dst = ei + N_EDGES;
    float* out = (float*)d_out;

    // workspace (byte offsets), total ~66 MB:
    // cnt 0x0 | inv 0x80000 | bsum 0x100000 | cursor 0x110000 |
    // spf(float4) 0x200000 (25.6MB) | b0 0x1B00000 (12.8MB half [N,64]) |
    // b1 0x2800000 (12.8MB) | b2 0x3500000 (12.8MB)
    char* ws = (char*)d_ws;
    int*    cnt    = (int*)(ws);
    float*  inv    = (float*)(ws + 0x80000);
    int*    bsum   = (int*)(ws + 0x100000);
    int*    cursor = (int*)(ws + 0x110000);
    float4* spf    = (float4*)(ws + 0x200000);
    __half* b0     = (__half*)(ws + 0x1B00000);
    __half* b1     = (__half*)(ws + 0x2800000);
    __half* b2     = (__half*)(ws + 0x3500000);

    const int NBLK = (N_NODES + 255) / 256;  // 391
    const int ABLK = 1024;                   // 4096 waves for pure aggs

    // graph preprocessing (shared by all 3 layers)
    hipMemsetAsync(cnt, 0, N_NODES * sizeof(int), stream);
    degree_kernel<<<2048, 256, 0, stream>>>(dst, cnt, N_EDGES);
    inv_kernel<<<NBLK, 256, 0, stream>>>(cnt, inv, N_NODES);
    block_sum_kernel<<<NBLK, 256, 0, stream>>>(cnt, bsum, N_NODES);
    scan_bsum_kernel<<<1, 512, 0, stream>>>(bsum, NBLK);
    make_cursor_kernel<<<NBLK, 256, 0, stream>>>(cnt, bsum, cursor, N_NODES);
    scatter_pack_kernel<<<2048, 256, 0, stream>>>(src, dst, ea, cursor, spf, N_EDGES);
    // cursor[n] = end offset of node n's CSR range

    // P1 = half(x @ W1a[0:6] + b1a) -> b0
    node_gemm6h<<<NBLK, 256, 0, stream>>>(x, W1a, b1a, b0, N_NODES);

    // ---- layer 1 ----
    agg64_pure<<<ABLK, 256, 0, stream>>>(b0, spf, cursor, cnt, inv, W1a + 6 * 64, b1, N_NODES);
    node_mlp_h<64, 64, true, true><<<NBLK, 256, 0, stream>>>(b1, W1b, b1b, inv, b2, N_NODES);
    node_mlp_h<64, 64, false, false><<<NBLK, 256, 0, stream>>>(b2, W2a, b2a, inv, b0, N_NODES);

    // ---- layer 2 ----
    agg64_pure<<<ABLK, 256, 0, stream>>>(b0, spf, cursor, cnt, inv, W2a + 64 * 64, b1, N_NODES);
    node_mlp_h<64, 64, true, true><<<NBLK, 256, 0, stream>>>(b1, W2b, b2b, inv, b2, N_NODES);
    node_mlp_h<64, 32, false, false><<<NBLK, 256, 0, stream>>>(b2, W3a, b3a, inv, b0, N_NODES);

    // ---- layer 3 ----
    agg32_pure<<<ABLK, 256, 0, stream>>>(b0, spf, cursor, cnt, inv, W3a + 64 * 32, b1, N_NODES);
    node_mlp_final<<<NBLK, 256, 0, stream>>>(b1, W3b, b3b, inv, out, N_NODES);
}

// Round 13
// 448.019 us; speedup vs baseline: 1.1345x; 1.0435x over previous
//
#include <hip/hip_runtime.h>
#include <hip/hip_fp16.h>

#define N_NODES 100000
#define N_EDGES 1600000

// ---------------- degree (XCD-partitioned) ----------------
__global__ __launch_bounds__(256) void degree_kernel(const int* __restrict__ dst,
                                                     int* __restrict__ cnt, int E) {
    const int range = blockIdx.x & 7;
    const int lo = range * (N_NODES / 8);
    const int hi = lo + (N_NODES / 8);
    int i = (blockIdx.x >> 3) * blockDim.x + threadIdx.x;
    const int stride = (gridDim.x >> 3) * blockDim.x;
    for (; i < E; i += stride) {
        const int d = dst[i];
        if (d >= lo && d < hi) atomicAdd(&cnt[d], 1);
    }
}

// ---------------- hierarchical exclusive scan (cnt -> cursor), inv fused -----
__global__ __launch_bounds__(256) void block_sum_kernel(const int* __restrict__ cnt,
                                                        int* __restrict__ bsum, int N) {
    __shared__ int s[256];
    const int tid = threadIdx.x;
    const int i = blockIdx.x * 256 + tid;
    s[tid] = (i < N) ? cnt[i] : 0;
    __syncthreads();
#pragma unroll
    for (int d = 128; d > 0; d >>= 1) {
        if (tid < d) s[tid] += s[tid + d];
        __syncthreads();
    }
    if (tid == 0) bsum[blockIdx.x] = s[0];
}

__global__ __launch_bounds__(512) void scan_bsum_kernel(int* __restrict__ bsum, int NB) {
    __shared__ int s[512];
    const int tid = threadIdx.x;
    const int v = (tid < NB) ? bsum[tid] : 0;
    s[tid] = v;
    __syncthreads();
    for (int d = 1; d < 512; d <<= 1) {
        const int t = (tid >= d) ? s[tid - d] : 0;
        __syncthreads();
        s[tid] += t;
        __syncthreads();
    }
    if (tid < NB) bsum[tid] = s[tid] - v;  // exclusive
}

__global__ __launch_bounds__(256) void make_cursor_kernel(const int* __restrict__ cnt,
                                                          const int* __restrict__ bsum,
                                                          int* __restrict__ cursor,
                                                          float* __restrict__ inv, int N) {
    __shared__ int s[256];
    const int tid = threadIdx.x;
    const int i = blockIdx.x * 256 + tid;
    const int v = (i < N) ? cnt[i] : 0;
    s[tid] = v;
    __syncthreads();
    for (int d = 1; d < 256; d <<= 1) {
        const int t = (tid >= d) ? s[tid - d] : 0;
        __syncthreads();
        s[tid] += t;
        __syncthreads();
    }
    if (i < N) {
        cursor[i] = bsum[blockIdx.x] + s[tid] - v;
        inv[i] = (v > 0) ? (1.0f / (float)v) : 0.0f;
    }
}

// ---------------- XCD-partitioned CSR scatter, float4 payload ----------------
__global__ __launch_bounds__(256) void scatter_pack_kernel(
    const int* __restrict__ src, const int* __restrict__ dst,
    const float* __restrict__ ea,
    int* __restrict__ cursor, float4* __restrict__ spf, int E) {
    const int range = blockIdx.x & 7;
    const int lo = range * (N_NODES / 8);
    const int hi = lo + (N_NODES / 8);
    int i = (blockIdx.x >> 3) * blockDim.x + threadIdx.x;
    const int stride = (gridDim.x >> 3) * blockDim.x;
    for (; i < E; i += stride) {
        const int d = dst[i];
        if (d >= lo && d < hi) {
            const int pos = atomicAdd(&cursor[d], 1);
            spf[pos] = make_float4(__int_as_float(src[i]),
                                   ea[3 * (size_t)i + 0],
                                   ea[3 * (size_t)i + 1],
                                   ea[3 * (size_t)i + 2]);
        }
    }
}

// ---------------- node GEMM: P1(half) = x @ W1a[0:6] + b1a ----------------
__global__ __launch_bounds__(256) void node_gemm6h(
    const float* __restrict__ x, const float* __restrict__ W,
    const float* __restrict__ bias, __half* __restrict__ out_, int N) {
    int n = blockIdx.x * blockDim.x + threadIdx.x;
    if (n >= N) return;
    const float* row = x + (size_t)n * 6;
    float v[6];
#pragma unroll
    for (int k = 0; k < 6; ++k) v[k] = row[k];
    __half2* orow = (__half2*)(out_ + (size_t)n * 64);
    for (int g = 0; g < 16; ++g) {
        float a0 = bias[4 * g + 0], a1 = bias[4 * g + 1];
        float a2 = bias[4 * g + 2], a3 = bias[4 * g + 3];
#pragma unroll
        for (int k = 0; k < 6; ++k) {
            const float m = v[k];
            const float* w = &W[k * 64 + 4 * g];
            a0 = fmaf(m, w[0], a0);
            a1 = fmaf(m, w[1], a1);
            a2 = fmaf(m, w[2], a2);
            a3 = fmaf(m, w[3], a3);
        }
        orow[2 * g]     = __floats2half2_rn(a0, a1);
        orow[2 * g + 1] = __floats2half2_rn(a2, a3);
    }
}

// ---------------- PURE aggregate, DIN=64 fp16, 8-lane-subgroup gather --------
__global__ __launch_bounds__(256) void agg64_pure(
    const __half* __restrict__ P,    // [N,64] half
    const float4* __restrict__ spf,  // [E] CSR-ordered (src, ea0, ea1, ea2)
    const int* __restrict__ cursor, const int* __restrict__ cnt,
    const float* __restrict__ inv,
    const float* __restrict__ We,    // [3,64]
    __half* __restrict__ A, int N) {
    const int lane  = threadIdx.x & 63;
    const int sub   = lane >> 3;   // 0..7 subgroup = edge slot
    const int p     = lane & 7;    // 0..7 column block (8 cols)
    const int gw    = (blockIdx.x * blockDim.x + threadIdx.x) >> 6;
    const int nwave = (gridDim.x * blockDim.x) >> 6;

    float we0[8], we1[8], we2[8];
#pragma unroll
    for (int k = 0; k < 8; ++k) {
        we0[k] = We[0 * 64 + 8 * p + k];
        we1[k] = We[1 * 64 + 8 * p + k];
        we2[k] = We[2 * 64 + 8 * p + k];
    }

    for (int n = gw; n < N; n += nwave) {
        const int end   = cursor[n];
        const int count = cnt[n];
        int j = end - count;
        const float s_inv = inv[n];

        float s0 = 0.f, s1 = 0.f, s2 = 0.f, s3 = 0.f;
        float s4 = 0.f, s5 = 0.f, s6 = 0.f, s7 = 0.f;

#define GRP8(base, valid)                                                        \
    {                                                                            \
        const int ei = (base) + sub;                                             \
        const float4 f = spf[ei < end ? ei : end - 1];                           \
        const float4 rawf = *(const float4*)((const __half*)P +                  \
                            ((size_t)__float_as_int(f.x) << 6) + 8 * p);         \
        const __half2* hp = (const __half2*)&rawf;                               \
        const float2 q0 = __half22float2(hp[0]);                                 \
        const float2 q1 = __half22float2(hp[1]);                                 \
        const float2 q2 = __half22float2(hp[2]);                                 \
        const float2 q3 = __half22float2(hp[3]);                                 \
        const float h0 = fmaxf(fmaf(f.w, we2[0], fmaf(f.z, we1[0], fmaf(f.y, we0[0], q0.x))), 0.f); \
        const float h1 = fmaxf(fmaf(f.w, we2[1], fmaf(f.z, we1[1], fmaf(f.y, we0[1], q0.y))), 0.f); \
        const float h2 = fmaxf(fmaf(f.w, we2[2], fmaf(f.z, we1[2], fmaf(f.y, we0[2], q1.x))), 0.f); \
        const float h3 = fmaxf(fmaf(f.w, we2[3], fmaf(f.z, we1[3], fmaf(f.y, we0[3], q1.y))), 0.f); \
        const float h4 = fmaxf(fmaf(f.w, we2[4], fmaf(f.z, we1[4], fmaf(f.y, we0[4], q2.x))), 0.f); \
        const float h5 = fmaxf(fmaf(f.w, we2[5], fmaf(f.z, we1[5], fmaf(f.y, we0[5], q2.y))), 0.f); \
        const float h6 = fmaxf(fmaf(f.w, we2[6], fmaf(f.z, we1[6], fmaf(f.y, we0[6], q3.x))), 0.f); \
        const float h7 = fmaxf(fmaf(f.w, we2[7], fmaf(f.z, we1[7], fmaf(f.y, we0[7], q3.y))), 0.f); \
        if (valid) {                                                             \
            s0 += h0; s1 += h1; s2 += h2; s3 += h3;                              \
            s4 += h4; s5 += h5; s6 += h6; s7 += h7;                              \
        }                                                                        \
    }

        for (; j + 16 <= end; j += 16) { GRP8(j, true) GRP8(j + 8, true) }
        if (j + 8 <= end) { GRP8(j, true) j += 8; }
        {
            const int rem = end - j;
            if (rem > 0) { GRP8(j, (sub < rem)) }
        }
#undef GRP8

#define RED(d) \
        s0 += __shfl_xor(s0, d); s1 += __shfl_xor(s1, d); \
        s2 += __shfl_xor(s2, d); s3 += __shfl_xor(s3, d); \
        s4 += __shfl_xor(s4, d); s5 += __shfl_xor(s5, d); \
        s6 += __shfl_xor(s6, d); s7 += __shfl_xor(s7, d);
        RED(8) RED(16) RED(32)
#undef RED

        if (lane < 8) {
            __half2 h01 = __floats2half2_rn(s0 * s_inv, s1 * s_inv);
            __half2 h23 = __floats2half2_rn(s2 * s_inv, s3 * s_inv);
            __half2 h45 = __floats2half2_rn(s4 * s_inv, s5 * s_inv);
            __half2 h67 = __floats2half2_rn(s6 * s_inv, s7 * s_inv);
            union { __half2 h[4]; float4 f; } u;
            u.h[0] = h01; u.h[1] = h23; u.h[2] = h45; u.h[3] = h67;
            *(float4*)(A + (size_t)n * 64 + 8 * p) = u.f;
        }
    }
}

// ---------------- PURE aggregate, DIN=32 fp16, 4-lane-subgroup gather --------
__global__ __launch_bounds__(256) void agg32_pure(
    const __half* __restrict__ P,    // [N,32] half
    const float4* __restrict__ spf,
    const int* __restrict__ cursor, const int* __restrict__ cnt,
    const float* __restrict__ inv,
    const float* __restrict__ We,    // [3,32]
    __half* __restrict__ A, int N) {
    const int lane  = threadIdx.x & 63;
    const int sub   = lane >> 2;   // 0..15 subgroup = edge slot
    const int p     = lane & 3;    // 0..3 column block (8 cols)
    const int gw    = (blockIdx.x * blockDim.x + threadIdx.x) >> 6;
    const int nwave = (gridDim.x * blockDim.x) >> 6;

    float we0[8], we1[8], we2[8];
#pragma unroll
    for (int k = 0; k < 8; ++k) {
        we0[k] = We[0 * 32 + 8 * p + k];
        we1[k] = We[1 * 32 + 8 * p + k];
        we2[k] = We[2 * 32 + 8 * p + k];
    }

    for (int n = gw; n < N; n += nwave) {
        const int end   = cursor[n];
        const int count = cnt[n];
        int j = end - count;
        const float s_inv = inv[n];

        float s0 = 0.f, s1 = 0.f, s2 = 0.f, s3 = 0.f;
        float s4 = 0.f, s5 = 0.f, s6 = 0.f, s7 = 0.f;

#define GRP16(base, valid)                                                       \
    {                                                                            \
        const int ei = (base) + sub;                                             \
        const float4 f = spf[ei < end ? ei : end - 1];                           \
        const float4 rawf = *(const float4*)((const __half*)P +                  \
                            ((size_t)__float_as_int(f.x) << 5) + 8 * p);         \
        const __half2* hp = (const __half2*)&rawf;                               \
        const float2 q0 = __half22float2(hp[0]);                                 \
        const float2 q1 = __half22float2(hp[1]);                                 \
        const float2 q2 = __half22float2(hp[2]);                                 \
        const float2 q3 = __half22float2(hp[3]);                                 \
        const float h0 = fmaxf(fmaf(f.w, we2[0], fmaf(f.z, we1[0], fmaf(f.y, we0[0], q0.x))), 0.f); \
        const float h1 = fmaxf(fmaf(f.w, we2[1], fmaf(f.z, we1[1], fmaf(f.y, we0[1], q0.y))), 0.f); \
        const float h2 = fmaxf(fmaf(f.w, we2[2], fmaf(f.z, we1[2], fmaf(f.y, we0[2], q1.x))), 0.f); \
        const float h3 = fmaxf(fmaf(f.w, we2[3], fmaf(f.z, we1[3], fmaf(f.y, we0[3], q1.y))), 0.f); \
        const float h4 = fmaxf(fmaf(f.w, we2[4], fmaf(f.z, we1[4], fmaf(f.y, we0[4], q2.x))), 0.f); \
        const float h5 = fmaxf(fmaf(f.w, we2[5], fmaf(f.z, we1[5], fmaf(f.y, we0[5], q2.y))), 0.f); \
        const float h6 = fmaxf(fmaf(f.w, we2[6], fmaf(f.z, we1[6], fmaf(f.y, we0[6], q3.x))), 0.f); \
        const float h7 = fmaxf(fmaf(f.w, we2[7], fmaf(f.z, we1[7], fmaf(f.y, we0[7], q3.y))), 0.f); \
        if (valid) {                                                             \
            s0 += h0; s1 += h1; s2 += h2; s3 += h3;                              \
            s4 += h4; s5 += h5; s6 += h6; s7 += h7;                              \
        }                                                                        \
    }

        for (; j + 16 <= end; j += 16) { GRP16(j, true) }
        {
            const int rem = end - j;
            if (rem > 0) { GRP16(j, (sub < rem)) }
        }
#undef GRP16

#define RED(d) \
        s0 += __shfl_xor(s0, d); s1 += __shfl_xor(s1, d); \
        s2 += __shfl_xor(s2, d); s3 += __shfl_xor(s3, d); \
        s4 += __shfl_xor(s4, d); s5 += __shfl_xor(s5, d); \
        s6 += __shfl_xor(s6, d); s7 += __shfl_xor(s7, d);
        RED(4) RED(8) RED(16) RED(32)
#undef RED

        if (lane < 4) {
            __half2 h01 = __floats2half2_rn(s0 * s_inv, s1 * s_inv);
            __half2 h23 = __floats2half2_rn(s2 * s_inv, s3 * s_inv);
            __half2 h45 = __floats2half2_rn(s4 * s_inv, s5 * s_inv);
            __half2 h67 = __floats2half2_rn(s6 * s_inv, s7 * s_inv);
            union { __half2 h[4]; float4 f; } u;
            u.h[0] = h01; u.h[1] = h23; u.h[2] = h45; u.h[3] = h67;
            *(float4*)(A + (size_t)n * 32 + 8 * p) = u.f;
        }
    }
}

// ---------------- fused double MLP: thread-per-node, s_load weights ----------
// m = relu(in[n]@W1 + b1*mask);  out[n] = m@W2 + b2   (fp16 in/out)
// Intermediate m packed to fp16 in registers (16 VGPRs) to avoid spill.
template <int OUT2>
__global__ __launch_bounds__(256) void node_mlp2(
    const __half* __restrict__ in_,
    const float* __restrict__ W1, const float* __restrict__ b1,
    const float* __restrict__ W2, const float* __restrict__ b2,
    const float* __restrict__ inv,
    __half* __restrict__ out_, int N) {
    int n = blockIdx.x * blockDim.x + threadIdx.x;
    if (n >= N) return;
    const __half* row = in_ + (size_t)n * 64;
    float v[64];
#pragma unroll
    for (int q = 0; q < 8; ++q) {
        float4 raw = ((const float4*)row)[q];
        const __half2* hp = (const __half2*)&raw;
#pragma unroll
        for (int t = 0; t < 4; ++t) {
            const float2 f2 = __half22float2(hp[t]);
            v[8 * q + 2 * t]     = f2.x;
            v[8 * q + 2 * t + 1] = f2.y;
        }
    }
    const float bs = (inv[n] != 0.0f) ? 1.0f : 0.0f;

    // GEMM1 -> packed fp16 intermediate
    __half2 mh[32];
    for (int g = 0; g < 16; ++g) {
        float a0 = b1[4 * g + 0] * bs, a1 = b1[4 * g + 1] * bs;
        float a2 = b1[4 * g + 2] * bs, a3 = b1[4 * g + 3] * bs;
#pragma unroll
        for (int k = 0; k < 64; ++k) {
            const float m = v[k];
            const float* w = &W1[k * 64 + 4 * g];
            a0 = fmaf(m, w[0], a0);
            a1 = fmaf(m, w[1], a1);
            a2 = fmaf(m, w[2], a2);
            a3 = fmaf(m, w[3], a3);
        }
        a0 = fmaxf(a0, 0.f); a1 = fmaxf(a1, 0.f);
        a2 = fmaxf(a2, 0.f); a3 = fmaxf(a3, 0.f);
        mh[2 * g]     = __floats2half2_rn(a0, a1);
        mh[2 * g + 1] = __floats2half2_rn(a2, a3);
    }
    // unpack back to v
#pragma unroll
    for (int t = 0; t < 32; ++t) {
        const float2 f2 = __half22float2(mh[t]);
        v[2 * t]     = f2.x;
        v[2 * t + 1] = f2.y;
    }
    // GEMM2 -> fp16 out
    __half2 hout[OUT2 / 2];
    for (int g = 0; g < OUT2 / 4; ++g) {
        float a0 = b2[4 * g + 0], a1 = b2[4 * g + 1];
        float a2 = b2[4 * g + 2], a3 = b2[4 * g + 3];
#pragma unroll
        for (int k = 0; k < 64; ++k) {
            const float m = v[k];
            const float* w = &W2[k * OUT2 + 4 * g];
            a0 = fmaf(m, w[0], a0);
            a1 = fmaf(m, w[1], a1);
            a2 = fmaf(m, w[2], a2);
            a3 = fmaf(m, w[3], a3);
        }
        hout[2 * g]     = __floats2half2_rn(a0, a1);
        hout[2 * g + 1] = __floats2half2_rn(a2, a3);
    }
    float4* orow = (float4*)(out_ + (size_t)n * OUT2);
#pragma unroll
    for (int q = 0; q < OUT2 / 8; ++q) orow[q] = ((const float4*)hout)[q];
}

// final: fp16 in -> fp32 out, masked bias, no relu
__global__ __launch_bounds__(256) void node_mlp_final(
    const __half* __restrict__ in_, const float* __restrict__ W,
    const float* __restrict__ bias, const float* __restrict__ inv,
    float* __restrict__ out_, int N) {
    int n = blockIdx.x * blockDim.x + threadIdx.x;
    if (n >= N) return;
    const __half* row = in_ + (size_t)n * 32;
    float v[32];
#pragma unroll
    for (int q = 0; q < 4; ++q) {
        float4 raw = ((const float4*)row)[q];
        const __half2* hp = (const __half2*)&raw;
#pragma unroll
        for (int t = 0; t < 4; ++t) {
            const float2 f2 = __half22float2(hp[t]);
            v[8 * q + 2 * t]     = f2.x;
            v[8 * q + 2 * t + 1] = f2.y;
        }
    }
    const float bs = (inv[n] != 0.0f) ? 1.0f : 0.0f;
    float* orow = out_ + (size_t)n * 32;
    for (int g = 0; g < 8; ++g) {
        float a0 = bias[4 * g + 0] * bs, a1 = bias[4 * g + 1] * bs;
        float a2 = bias[4 * g + 2] * bs, a3 = bias[4 * g + 3] * bs;
#pragma unroll
        for (int k = 0; k < 32; ++k) {
            const float m = v[k];
            const float* w = &W[k * 32 + 4 * g];
            a0 = fmaf(m, w[0], a0);
            a1 = fmaf(m, w[1], a1);
            a2 = fmaf(m, w[2], a2);
            a3 = fmaf(m, w[3], a3);
        }
        ((float4*)orow)[g] = make_float4(a0, a1, a2, a3);
    }
}

extern "C" void kernel_launch(void* const* d_in, const int* in_sizes, int n_in,
                              void* d_out, int out_size, void* d_ws, size_t ws_size,
                              hipStream_t stream) {
    const float* x   = (const float*)d_in[0];
    const int*   ei  = (const int*)d_in[1];
    const float* ea  = (const float*)d_in[2];
    const float* W1a = (const float*)d_in[3];
    const float* b1a = (const float*)d_in[4];
    const float* W1b = (const float*)d_in[5];
    const float* b1b = (const float*)d_in[6];
    const float* W2a = (const float*)d_in[7];
    const float* b2a = (const float*)d_in[8];
    const float* W2b = (const float*)d_in[9];
    const float* b2b = (const float*)d_in[10];
    const float* W3a = (const float*)d_in[11];
    const float* b3a = (const float*)d_in[12];
    const float* W3b = (const float*)d_in[13];
    const float* b3b = (const float*)d_in[14];

    const int* src = ei;
    const int* dst = ei + N_EDGES;
    float* out = (float*)d_out;

    // workspace (byte offsets), total ~66 MB:
    // cnt 0x0 | inv 0x80000 | bsum 0x100000 | cursor 0x110000 |
    // spf(float4) 0x200000 (25.6MB) | b0 0x1B00000 (12.8MB half [N,64]) |
    // b1 0x2800000 (12.8MB) | b2 0x3500000 (12.8MB)
    char* ws = (char*)d_ws;
    int*    cnt    = (int*)(ws);
    float*  inv    = (float*)(ws + 0x80000);
    int*    bsum   = (int*)(ws + 0x100000);
    int*    cursor = (int*)(ws + 0x110000);
    float4* spf    = (float4*)(ws + 0x200000);
    __half* b0     = (__half*)(ws + 0x1B00000);
    __half* b1     = (__half*)(ws + 0x2800000);

    const int NBLK = (N_NODES + 255) / 256;  // 391
    const int ABLK = 1024;                   // 4096 waves for pure aggs

    // graph preprocessing (shared by all 3 layers)
    hipMemsetAsync(cnt, 0, N_NODES * sizeof(int), stream);
    degree_kernel<<<2048, 256, 0, stream>>>(dst, cnt, N_EDGES);
    block_sum_kernel<<<NBLK, 256, 0, stream>>>(cnt, bsum, N_NODES);
    scan_bsum_kernel<<<1, 512, 0, stream>>>(bsum, NBLK);
    make_cursor_kernel<<<NBLK, 256, 0, stream>>>(cnt, bsum, cursor, inv, N_NODES);
    scatter_pack_kernel<<<2048, 256, 0, stream>>>(src, dst, ea, cursor, spf, N_EDGES);
    // cursor[n] = end offset of node n's CSR range

    // P1 = half(x @ W1a[0:6] + b1a) -> b0
    node_gemm6h<<<NBLK, 256, 0, stream>>>(x, W1a, b1a, b0, N_NODES);

    // ---- layer 1 ----
    agg64_pure<<<ABLK, 256, 0, stream>>>(b0, spf, cursor, cnt, inv, W1a + 6 * 64, b1, N_NODES);
    node_mlp2<64><<<NBLK, 256, 0, stream>>>(b1, W1b, b1b, W2a, b2a, inv, b0, N_NODES);

    // ---- layer 2 ----
    agg64_pure<<<ABLK, 256, 0, stream>>>(b0, spf, cursor, cnt, inv, W2a + 64 * 64, b1, N_NODES);
    node_mlp2<32><<<NBLK, 256, 0, stream>>>(b1, W2b, b2b, W3a, b3a, inv, b0, N_NODES);

    // ---- layer 3 ----
    agg32_pure<<<ABLK, 256, 0, stream>>>(b0, spf, cursor, cnt, inv, W3a + 64 * 32, b1, N_NODES);
    node_mlp_final<<<NBLK, 256, 0, stream>>>(b1, W3b, b3b, inv, out, N_NODES);
}